// Round 6
// baseline (597.102 us; speedup 1.0000x reference)
//
#include <hip/hip_runtime.h>
#include <math.h>

#define N_ROWS 4096
#define E_DIM  512
#define C_CLS  50257
#define NCH    786            // ceil(50257/64) col chunks of 64
#define NGRP   16             // col groups (blockIdx.y); pl = [N_ROWS][NGRP]
#define COS_M  (-0.6536436208636119f)   // cos(4.0)
#define SIN_M  (-0.7568024953079282f)   // sin(4.0)
#define EPSN   1e-12f

typedef __bf16 bf16x8 __attribute__((ext_vector_type(8)));
typedef float  f32x4  __attribute__((ext_vector_type(4)));
typedef unsigned short ushort8 __attribute__((ext_vector_type(8)));

__device__ inline unsigned short f2bf(float f) {
  unsigned int u = __float_as_uint(f);
  u += 0x7FFFu + ((u >> 16) & 1u);     // round-to-nearest-even
  return (unsigned short)(u >> 16);
}
__device__ inline float bf2f(unsigned short u) {
  return __uint_as_float((unsigned)u << 16);
}

// Fused normalize kernel:
//  blocks [0, N_ROWS)            : x-row L2-normalize + fp32 target cos tv +
//                                  bf16-rounded target cos tb.
//  blocks [N_ROWS, ...)          : w-row L2-normalize (4 rows/block).
__global__ __launch_bounds__(256) void k_norm(const float* __restrict__ x,
                                              const float* __restrict__ w,
                                              const int* __restrict__ label,
                                              unsigned short* __restrict__ nx,
                                              unsigned short* __restrict__ nw,
                                              float* __restrict__ tv,
                                              float* __restrict__ tb) {
  if (blockIdx.x >= N_ROWS) {
    int row = (blockIdx.x - N_ROWS) * 4 + (threadIdx.x >> 6);
    if (row >= C_CLS) return;
    int lane = threadIdx.x & 63;
    const float4* p = (const float4*)(w + (size_t)row * E_DIM);
    float4 v0 = p[lane * 2], v1 = p[lane * 2 + 1];
    float ss = v0.x*v0.x + v0.y*v0.y + v0.z*v0.z + v0.w*v0.w
             + v1.x*v1.x + v1.y*v1.y + v1.z*v1.z + v1.w*v1.w;
    #pragma unroll
    for (int m = 32; m > 0; m >>= 1) ss += __shfl_xor(ss, m, 64);
    float inv = 1.0f / fmaxf(sqrtf(ss), EPSN);
    ushort8 o;
    o[0]=f2bf(v0.x*inv); o[1]=f2bf(v0.y*inv); o[2]=f2bf(v0.z*inv); o[3]=f2bf(v0.w*inv);
    o[4]=f2bf(v1.x*inv); o[5]=f2bf(v1.y*inv); o[6]=f2bf(v1.z*inv); o[7]=f2bf(v1.w*inv);
    *(ushort8*)(nw + (size_t)row * E_DIM + lane * 8) = o;
    return;
  }
  int row = blockIdx.x;
  int lab = label[row];
  int tid = threadIdx.x;
  const float2* px = (const float2*)(x + (size_t)row * E_DIM);
  const float2* pw = (const float2*)(w + (size_t)lab * E_DIM);
  float2 a = px[tid], b = pw[tid];
  float sx = a.x*a.x + a.y*a.y;
  float sw = b.x*b.x + b.y*b.y;
  float sd = a.x*b.x + a.y*b.y;
  #pragma unroll
  for (int off = 32; off > 0; off >>= 1) {
    sx += __shfl_down(sx, off, 64);
    sw += __shfl_down(sw, off, 64);
    sd += __shfl_down(sd, off, 64);
  }
  __shared__ float sb[3][4];
  __shared__ float sb2[4];
  if ((tid & 63) == 0) {
    sb[0][tid >> 6] = sx; sb[1][tid >> 6] = sw; sb[2][tid >> 6] = sd;
  }
  __syncthreads();
  float SX = sb[0][0] + sb[0][1] + sb[0][2] + sb[0][3];
  float SW = sb[1][0] + sb[1][1] + sb[1][2] + sb[1][3];
  float invx = 1.0f / fmaxf(sqrtf(SX), EPSN);
  float invw = 1.0f / fmaxf(sqrtf(SW), EPSN);
  ushort2 o;
  o.x = f2bf(a.x * invx);
  o.y = f2bf(a.y * invx);
  ((ushort2*)(nx + (size_t)row * E_DIM))[tid] = o;
  float s2 = bf2f(o.x) * bf2f(f2bf(b.x * invw))
           + bf2f(o.y) * bf2f(f2bf(b.y * invw));
  #pragma unroll
  for (int off = 32; off > 0; off >>= 1) s2 += __shfl_down(s2, off, 64);
  if ((tid & 63) == 0) sb2[tid >> 6] = s2;
  __syncthreads();
  if (tid == 0) {
    float SD = sb[2][0] + sb[2][1] + sb[2][2] + sb[2][3];
    tv[row] = SD / (fmaxf(sqrtf(SX), EPSN) * fmaxf(sqrtf(SW), EPSN));
    tb[row] = sb2[0] + sb2[1] + sb2[2] + sb2[3];
  }
}

// ---------------------------------------------------------------------------
// Persistent column-streaming GEMM, DUAL-PORT B feed — queue-order-corrected.
//
// Round-5 failure mechanism: staging GLDS issued BEFORE direct loads in the
// vmcnt queue -> consuming a direct load (vmcnt~1) drained the older staging
// ops -> stage/compute serialized (observed: HBM == demand rate, MfmaUtil 28%).
// vmcnt retires strictly in issue order (m135), so the fix is queue discipline:
//
// Per chunk body (order matters):
//   1. 16 direct B-frags (cols 48-63, one per ks) via volatile-asm
//      global_load_dwordx4 (oldest in queue; compiler can't sink/reorder).
//   2. stageB(c+1): 6 global_load_lds (younger).
//   3. LDS MFMA loop (cols 0-47): ds_read + MFMA only — no vmem consumption,
//      no vmcnt waits; gives the directs ~4K cycles to land.
//   4. s_waitcnt vmcnt(6): the 16 directs retired, 6 staging ops STAY IN
//      FLIGHT (vmcnt(0) on the last chunk). sched_barrier(0) after it (rule
//      18: stop register-only MFMAs hoisting above the wait).
//   5. direct MFMA loop: acc[rf][3] += mfma(a[rf][ks], dcur[ks]).
//   6. exp epilogue (interior: unmasked; tail chunk: col<C_CLS mask).
//   7. __syncthreads (drains stage c+1 after a full chunk of overlap).
//
// Floors: LDS 48 reads/wave/chunk ~5.1K cyc, MFMA 5.0K, direct 32 KB/chunk
// working set L1-served. A-slab (32 rows x K=512 = 128 regs) pinned via
// volatile-asm loads (round-3/4 lesson). OOB columns in group 15's tail read
// into workspace (tv/tb/pl follow nw) and are masked in the tail epilogue.
// ---------------------------------------------------------------------------
#define GLDS(gp, lp) __builtin_amdgcn_global_load_lds( \
    (const __attribute__((address_space(1))) void*)(gp), \
    (__attribute__((address_space(3))) void*)(lp), 16, 0, 0)

__global__ __launch_bounds__(512, 2) void k_gemm(const unsigned short* __restrict__ nx,
                                                 const unsigned short* __restrict__ nw,
                                                 float* __restrict__ pl) {
  __shared__ unsigned char ldsB[2][49152];   // 2 x (48 cols x 512 k x 2 B)

  const int rtile = blockIdx.x;              // 0..15
  const int grp   = blockIdx.y;              // 0..15
  const int c0    = grp * 49 + (grp < 2 ? grp : 2);   // chunk range [c0, c1)
  const int c1    = c0 + 49 + (grp < 2 ? 1 : 0);      // groups 0,1 take 50

  const int tid  = threadIdx.x;
  const int wave = tid >> 6;
  const int lane = tid & 63;
  const int q    = lane >> 4;
  const int l15  = lane & 15;
  const int row0 = rtile * 256 + wave * 32;  // wave's first output row

  // LDS portion: cols [c*64, c*64+48), 48 fragment chunks of 1 KB.
  auto stageB = [&](int c, int p) {
    unsigned cb = (unsigned)c * 64u;
    #pragma unroll
    for (int i = 0; i < 6; i++) {
      int ch = wave * 6 + i;                 // wave-uniform
      unsigned col = cb + (unsigned)((ch >> 4) * 16 + l15);
      unsigned off = col * (unsigned)E_DIM + (unsigned)((ch & 15) * 32 + q * 8);
      GLDS(nw + off, &ldsB[p][ch * 1024]);   // OOB (grp 15 tail) lands in ws
    }
  };

  // Issue first LDS stage, then load A-slab while it flies.
  stageB(c0, c0 & 1);

  // A-slab: 32 rows x K=512 pinned in registers via volatile asm loads.
  f32x4 araw[2][16];
  #pragma unroll
  for (int rf = 0; rf < 2; rf++)
    #pragma unroll
    for (int kf = 0; kf < 16; kf++) {
      const unsigned short* pa = nx + (size_t)(row0 + rf * 16 + l15) * E_DIM
                                    + kf * 32 + q * 8;
      asm volatile("global_load_dwordx4 %0, %1, off"
                   : "=v"(araw[rf][kf]) : "v"(pa));
    }
  asm volatile("s_waitcnt vmcnt(0)" ::: "memory");
  bf16x8 a[2][16];
  #pragma unroll
  for (int rf = 0; rf < 2; rf++)
    #pragma unroll
    for (int kf = 0; kf < 16; kf++)
      a[rf][kf] = __builtin_bit_cast(bf16x8, araw[rf][kf]);

  float e[8] = {};                           // per-lane partial exp-sums

  // Direct-path base: col = c*64 + 48 + l15, elems q*8; +ks*64 B via offset.
  const unsigned short* dptr = nw + (size_t)((size_t)c0 * 64 + 48 + l15) * E_DIM
                                  + q * 8;

  __syncthreads();                           // chunk c0 landed everywhere

  for (int c = c0; c < c1; ++c) {
    const int p = c & 1;

    // (1) direct loads — OLDEST in this chunk's vmcnt queue.
    f32x4 draw[16];
    #pragma unroll
    for (int ks = 0; ks < 16; ks++)
      asm volatile("global_load_dwordx4 %0, %1, off offset:%2"
                   : "=v"(draw[ks]) : "v"(dptr), "i"(ks * 64));

    // (2) stage next chunk — younger than the directs.
    if (c + 1 < c1) stageB(c + 1, p ^ 1);

    // (3) LDS MFMA loop (cols 0-47): no vmem consumption.
    f32x4 acc[2][4] = {};
    const unsigned char* bb = &ldsB[p][0];
    #pragma unroll
    for (int ks = 0; ks < 16; ks++) {
      bf16x8 bfr[3];
      #pragma unroll
      for (int cf = 0; cf < 3; cf++)
        bfr[cf] = *(const bf16x8*)(bb + (unsigned)((cf * 16 + ks) * 1024)
                                      + (unsigned)lane * 16u);
      #pragma unroll
      for (int rf = 0; rf < 2; rf++)
        #pragma unroll
        for (int cf = 0; cf < 3; cf++)
          acc[rf][cf] = __builtin_amdgcn_mfma_f32_16x16x32_bf16(
              a[rf][ks], bfr[cf], acc[rf][cf], 0, 0, 0);
    }

    // (4) counted wait: directs retired, staging stays in flight.
    if (c + 1 < c1) asm volatile("s_waitcnt vmcnt(6)" ::: "memory");
    else            asm volatile("s_waitcnt vmcnt(0)" ::: "memory");
    __builtin_amdgcn_sched_barrier(0);       // rule 18: pin MFMAs below wait

    // (5) direct MFMA loop (cols 48-63).
    #pragma unroll
    for (int ks = 0; ks < 16; ks++) {
      bf16x8 dfr = __builtin_bit_cast(bf16x8, draw[ks]);
      #pragma unroll
      for (int rf = 0; rf < 2; rf++)
        acc[rf][3] = __builtin_amdgcn_mfma_f32_16x16x32_bf16(
            a[rf][ks], dfr, acc[rf][3], 0, 0, 0);
    }

    // (6) exp epilogue: unmasked interior, masked tail.
    if (c != NCH - 1) {
      #pragma unroll
      for (int rf = 0; rf < 2; rf++)
        #pragma unroll
        for (int r = 0; r < 4; r++)
          #pragma unroll
          for (int cf = 0; cf < 4; cf++)
            e[rf * 4 + r] += __expf(acc[rf][cf][r]);
    } else {
      const int ccol = c * 64;
      #pragma unroll
      for (int rf = 0; rf < 2; rf++)
        #pragma unroll
        for (int r = 0; r < 4; r++)
          #pragma unroll
          for (int cf = 0; cf < 4; cf++) {
            int col = ccol + cf * 16 + l15;
            if (col < C_CLS) e[rf * 4 + r] += __expf(acc[rf][cf][r]);
          }
    }

    dptr += (size_t)64 * E_DIM;              // advance direct base one chunk
    __syncthreads();                         // drains stage c+1 (full-chunk
                                             // overlap); rotates buffers
  }

  // Once-per-block reduce of e over the 16-lane col group + pl store.
  #pragma unroll
  for (int i = 0; i < 8; i++) {
    float s = e[i];
    #pragma unroll
    for (int m = 1; m < 16; m <<= 1) s += __shfl_xor(s, m, 64);
    if (l15 == 0) {
      int grow = row0 + (i >> 2) * 16 + 4 * q + (i & 3);
      pl[(size_t)grow * NGRP + grp] = s;
    }
  }
}

// Single block, 1024 threads: 4 rows/thread, block-reduce, direct store.
// No memset dispatch, no atomics.
__global__ __launch_bounds__(1024) void k_reduce(const float* __restrict__ pl,
                                                 const float* __restrict__ tv,
                                                 const float* __restrict__ tb,
                                                 float* __restrict__ out) {
  int tid = threadIdx.x;
  float acc = 0.f;
  for (int row = tid; row < N_ROWS; row += 1024) {
    const float4* p = (const float4*)(pl + (size_t)row * NGRP);
    float4 s0 = p[0], s1 = p[1], s2 = p[2], s3 = p[3];
    float S = (s0.x + s0.y + s0.z + s0.w) + (s1.x + s1.y + s1.z + s1.w)
            + (s2.x + s2.y + s2.z + s2.w) + (s3.x + s3.y + s3.z + s3.w);
    float t = tv[row];
    float tbl = tb[row];
    float sint = sqrtf(fmaxf(0.f, 1.f - t * t));
    float cosm = t * COS_M - sint * SIN_M;
    float Sp = S - __expf(tbl) + __expf(cosm);
    acc += logf(Sp) - cosm;
  }
  #pragma unroll
  for (int m = 32; m > 0; m >>= 1) acc += __shfl_xor(acc, m, 64);
  __shared__ float sb[16];
  if ((tid & 63) == 0) sb[tid >> 6] = acc;
  __syncthreads();
  if (tid == 0) {
    float S = 0.f;
    #pragma unroll
    for (int i = 0; i < 16; i++) S += sb[i];
    out[0] = S * (1.0f / N_ROWS);
  }
}

extern "C" void kernel_launch(void* const* d_in, const int* in_sizes, int n_in,
                              void* d_out, int out_size, void* d_ws, size_t ws_size,
                              hipStream_t stream) {
  const float* x = (const float*)d_in[0];
  const int* label = (const int*)d_in[1];
  const float* w = (const float*)d_in[2];
  float* out = (float*)d_out;
  char* ws = (char*)d_ws;

  size_t off = 0;
  unsigned short* nx = (unsigned short*)(ws + off); off += (size_t)N_ROWS * E_DIM * 2;  // 4 MB
  unsigned short* nw = (unsigned short*)(ws + off); off += (size_t)C_CLS * E_DIM * 2;   // 51.5 MB
  float* tv  = (float*)(ws + off); off += (size_t)N_ROWS * 4;
  float* tb  = (float*)(ws + off); off += (size_t)N_ROWS * 4;
  float* pl  = (float*)(ws + off); off += (size_t)N_ROWS * NGRP * 4;                    // 256 KB

  int nwBlocks = (C_CLS + 3) / 4;
  k_norm<<<N_ROWS + nwBlocks, 256, 0, stream>>>(x, w, label, nx, nw, tv, tb);
  dim3 g(16, 16);
  k_gemm<<<g, 512, 0, stream>>>(nx, nw, pl);
  k_reduce<<<1, 1024, 0, stream>>>(pl, tv, tb, out);
}

// Round 7
// 594.022 us; speedup vs baseline: 1.0052x; 1.0052x over previous
//
#include <hip/hip_runtime.h>
#include <math.h>

#define N_ROWS 4096
#define E_DIM  512
#define C_CLS  50257
#define NCH    786            // ceil(50257/64) col chunks of 64
#define NGRP   16             // col groups (blockIdx.y); pl = [N_ROWS][NGRP]
#define COS_M  (-0.6536436208636119f)   // cos(4.0)
#define SIN_M  (-0.7568024953079282f)   // sin(4.0)
#define EPSN   1e-12f

typedef __bf16 bf16x8 __attribute__((ext_vector_type(8)));
typedef float  f32x4  __attribute__((ext_vector_type(4)));
typedef unsigned short ushort8 __attribute__((ext_vector_type(8)));

__device__ inline unsigned short f2bf(float f) {
  unsigned int u = __float_as_uint(f);
  u += 0x7FFFu + ((u >> 16) & 1u);     // round-to-nearest-even
  return (unsigned short)(u >> 16);
}
__device__ inline float bf2f(unsigned short u) {
  return __uint_as_float((unsigned)u << 16);
}

// Fused normalize kernel:
//  blocks [0, N_ROWS)   : x-row L2-normalize + fp32 target cos tv +
//                         bf16-rounded target cos tb.
//  blocks [N_ROWS, ...) : w-row L2-normalize (4 rows/block).
__global__ __launch_bounds__(256) void k_norm(const float* __restrict__ x,
                                              const float* __restrict__ w,
                                              const int* __restrict__ label,
                                              unsigned short* __restrict__ nx,
                                              unsigned short* __restrict__ nw,
                                              float* __restrict__ tv,
                                              float* __restrict__ tb) {
  if (blockIdx.x >= N_ROWS) {
    int row = (blockIdx.x - N_ROWS) * 4 + (threadIdx.x >> 6);
    if (row >= C_CLS) return;
    int lane = threadIdx.x & 63;
    const float4* p = (const float4*)(w + (size_t)row * E_DIM);
    float4 v0 = p[lane * 2], v1 = p[lane * 2 + 1];
    float ss = v0.x*v0.x + v0.y*v0.y + v0.z*v0.z + v0.w*v0.w
             + v1.x*v1.x + v1.y*v1.y + v1.z*v1.z + v1.w*v1.w;
    #pragma unroll
    for (int m = 32; m > 0; m >>= 1) ss += __shfl_xor(ss, m, 64);
    float inv = 1.0f / fmaxf(sqrtf(ss), EPSN);
    ushort8 o;
    o[0]=f2bf(v0.x*inv); o[1]=f2bf(v0.y*inv); o[2]=f2bf(v0.z*inv); o[3]=f2bf(v0.w*inv);
    o[4]=f2bf(v1.x*inv); o[5]=f2bf(v1.y*inv); o[6]=f2bf(v1.z*inv); o[7]=f2bf(v1.w*inv);
    *(ushort8*)(nw + (size_t)row * E_DIM + lane * 8) = o;
    return;
  }
  int row = blockIdx.x;
  int lab = label[row];
  int tid = threadIdx.x;
  const float2* px = (const float2*)(x + (size_t)row * E_DIM);
  const float2* pw = (const float2*)(w + (size_t)lab * E_DIM);
  float2 a = px[tid], b = pw[tid];
  float sx = a.x*a.x + a.y*a.y;
  float sw = b.x*b.x + b.y*b.y;
  float sd = a.x*b.x + a.y*b.y;
  #pragma unroll
  for (int off = 32; off > 0; off >>= 1) {
    sx += __shfl_down(sx, off, 64);
    sw += __shfl_down(sw, off, 64);
    sd += __shfl_down(sd, off, 64);
  }
  __shared__ float sb[3][4];
  __shared__ float sb2[4];
  if ((tid & 63) == 0) {
    sb[0][tid >> 6] = sx; sb[1][tid >> 6] = sw; sb[2][tid >> 6] = sd;
  }
  __syncthreads();
  float SX = sb[0][0] + sb[0][1] + sb[0][2] + sb[0][3];
  float SW = sb[1][0] + sb[1][1] + sb[1][2] + sb[1][3];
  float invx = 1.0f / fmaxf(sqrtf(SX), EPSN);
  float invw = 1.0f / fmaxf(sqrtf(SW), EPSN);
  ushort2 o;
  o.x = f2bf(a.x * invx);
  o.y = f2bf(a.y * invx);
  ((ushort2*)(nx + (size_t)row * E_DIM))[tid] = o;
  float s2 = bf2f(o.x) * bf2f(f2bf(b.x * invw))
           + bf2f(o.y) * bf2f(f2bf(b.y * invw));
  #pragma unroll
  for (int off = 32; off > 0; off >>= 1) s2 += __shfl_down(s2, off, 64);
  if ((tid & 63) == 0) sb2[tid >> 6] = s2;
  __syncthreads();
  if (tid == 0) {
    float SD = sb[2][0] + sb[2][1] + sb[2][2] + sb[2][3];
    tv[row] = SD / (fmaxf(sqrtf(SX), EPSN) * fmaxf(sqrtf(SW), EPSN));
    tb[row] = sb2[0] + sb2[1] + sb2[2] + sb2[3];
  }
}

// ---------------------------------------------------------------------------
// Persistent column-streaming GEMM, DUAL-PORT B feed — register-cap fixed.
//
// Round-6 failure: __launch_bounds__(512, 2) behaves as 2 BLOCKS/CU (CUDA
// semantics; observed VGPR cap 128 = 512-reg SIMD pool / 4 waves) -> the
// ~240-reg live set spilled to scratch (WRITE_SIZE 6.9 MB) -> spill-reloads
// forced vmcnt drains -> serialized (MfmaUtil 19%). Fix: (512, 1) -> 2
// waves/SIMD -> 256-reg cap. LDS (96 KB x 2 > 160 KB) caps us at 1 block/CU
// regardless, so nothing is lost. Budget: A 128 + draw 64 + bfr 24 + e 8 +
// addr ~15 = ~240 arch, acc in AGPRs.
//
// Per chunk (queue order is the correctness of the pipeline):
//   1. 16 direct B-frags (cols 48-63, one per ks) via volatile-asm
//      global_load_dwordx4 — OLDEST in the vmcnt queue.
//   2. stageB(c+1): 6 global_load_lds — younger.
//   3. LDS MFMA loop (cols 0-47): ds_read + MFMA only, no vmem waits;
//      gives the directs ~4K cycles to land.
//   4. s_waitcnt vmcnt(6): directs retired, staging STAYS IN FLIGHT
//      (vmcnt(0) only on the last chunk). sched_barrier(0) after (rule 18).
//   5. direct MFMA loop: acc[rf][3] += mfma(a[rf][ks], draw[ks]).
//   6. exp epilogue (interior unmasked; tail chunk masks col >= C_CLS).
//   7. __syncthreads — drains own stage (issued a full chunk ago).
//
// Floors: LDS 432 KB/chunk ~5.1K cyc, vector 128 KB ~2.1K, MFMA 5.0K.
// ---------------------------------------------------------------------------
#define GLDS(gp, lp) __builtin_amdgcn_global_load_lds( \
    (const __attribute__((address_space(1))) void*)(gp), \
    (__attribute__((address_space(3))) void*)(lp), 16, 0, 0)

__global__ __launch_bounds__(512, 1) void k_gemm(const unsigned short* __restrict__ nx,
                                                 const unsigned short* __restrict__ nw,
                                                 float* __restrict__ pl) {
  __shared__ unsigned char ldsB[2][49152];   // 2 x (48 cols x 512 k x 2 B)

  const int rtile = blockIdx.x;              // 0..15
  const int grp   = blockIdx.y;              // 0..15
  const int c0    = grp * 49 + (grp < 2 ? grp : 2);   // chunk range [c0, c1)
  const int c1    = c0 + 49 + (grp < 2 ? 1 : 0);      // groups 0,1 take 50

  const int tid  = threadIdx.x;
  const int wave = tid >> 6;
  const int lane = tid & 63;
  const int q    = lane >> 4;
  const int l15  = lane & 15;
  const int row0 = rtile * 256 + wave * 32;  // wave's first output row

  // LDS portion: cols [c*64, c*64+48), 48 fragment chunks of 1 KB.
  auto stageB = [&](int c, int p) {
    unsigned cb = (unsigned)c * 64u;
    #pragma unroll
    for (int i = 0; i < 6; i++) {
      int ch = wave * 6 + i;                 // wave-uniform
      unsigned col = cb + (unsigned)((ch >> 4) * 16 + l15);
      unsigned off = col * (unsigned)E_DIM + (unsigned)((ch & 15) * 32 + q * 8);
      GLDS(nw + off, &ldsB[p][ch * 1024]);   // OOB (grp 15 tail) lands in ws
    }
  };

  // Issue first LDS stage, then load A-slab while it flies.
  stageB(c0, c0 & 1);

  // A-slab: 32 rows x K=512 pinned in registers via volatile asm loads.
  f32x4 araw[2][16];
  #pragma unroll
  for (int rf = 0; rf < 2; rf++)
    #pragma unroll
    for (int kf = 0; kf < 16; kf++) {
      const unsigned short* pa = nx + (size_t)(row0 + rf * 16 + l15) * E_DIM
                                    + kf * 32 + q * 8;
      asm volatile("global_load_dwordx4 %0, %1, off"
                   : "=v"(araw[rf][kf]) : "v"(pa));
    }
  asm volatile("s_waitcnt vmcnt(0)" ::: "memory");
  bf16x8 a[2][16];
  #pragma unroll
  for (int rf = 0; rf < 2; rf++)
    #pragma unroll
    for (int kf = 0; kf < 16; kf++)
      a[rf][kf] = __builtin_bit_cast(bf16x8, araw[rf][kf]);

  float e[8] = {};                           // per-lane partial exp-sums

  // Direct-path base: col = c*64 + 48 + l15, elems q*8; +ks*64 B via offset.
  const unsigned short* dptr = nw + (size_t)((size_t)c0 * 64 + 48 + l15) * E_DIM
                                  + q * 8;

  __syncthreads();                           // chunk c0 landed everywhere

  for (int c = c0; c < c1; ++c) {
    const int p = c & 1;

    // (1) direct loads — OLDEST in this chunk's vmcnt queue.
    f32x4 draw[16];
    #pragma unroll
    for (int ks = 0; ks < 16; ks++)
      asm volatile("global_load_dwordx4 %0, %1, off offset:%2"
                   : "=v"(draw[ks]) : "v"(dptr), "i"(ks * 64));

    // (2) stage next chunk — younger than the directs.
    if (c + 1 < c1) stageB(c + 1, p ^ 1);

    // (3) LDS MFMA loop (cols 0-47): no vmem consumption.
    f32x4 acc[2][4] = {};
    const unsigned char* bb = &ldsB[p][0];
    #pragma unroll
    for (int ks = 0; ks < 16; ks++) {
      bf16x8 bfr[3];
      #pragma unroll
      for (int cf = 0; cf < 3; cf++)
        bfr[cf] = *(const bf16x8*)(bb + (unsigned)((cf * 16 + ks) * 1024)
                                      + (unsigned)lane * 16u);
      #pragma unroll
      for (int rf = 0; rf < 2; rf++)
        #pragma unroll
        for (int cf = 0; cf < 3; cf++)
          acc[rf][cf] = __builtin_amdgcn_mfma_f32_16x16x32_bf16(
              a[rf][ks], bfr[cf], acc[rf][cf], 0, 0, 0);
    }

    // (4) counted wait: directs retired, staging stays in flight.
    if (c + 1 < c1) asm volatile("s_waitcnt vmcnt(6)" ::: "memory");
    else            asm volatile("s_waitcnt vmcnt(0)" ::: "memory");
    __builtin_amdgcn_sched_barrier(0);       // rule 18: pin MFMAs below wait

    // (5) direct MFMA loop (cols 48-63).
    #pragma unroll
    for (int ks = 0; ks < 16; ks++) {
      bf16x8 dfr = __builtin_bit_cast(bf16x8, draw[ks]);
      #pragma unroll
      for (int rf = 0; rf < 2; rf++)
        acc[rf][3] = __builtin_amdgcn_mfma_f32_16x16x32_bf16(
            a[rf][ks], dfr, acc[rf][3], 0, 0, 0);
    }

    // (6) exp epilogue: unmasked interior, masked tail.
    if (c != NCH - 1) {
      #pragma unroll
      for (int rf = 0; rf < 2; rf++)
        #pragma unroll
        for (int r = 0; r < 4; r++)
          #pragma unroll
          for (int cf = 0; cf < 4; cf++)
            e[rf * 4 + r] += __expf(acc[rf][cf][r]);
    } else {
      const int ccol = c * 64;
      #pragma unroll
      for (int rf = 0; rf < 2; rf++)
        #pragma unroll
        for (int r = 0; r < 4; r++)
          #pragma unroll
          for (int cf = 0; cf < 4; cf++) {
            int col = ccol + cf * 16 + l15;
            if (col < C_CLS) e[rf * 4 + r] += __expf(acc[rf][cf][r]);
          }
    }

    dptr += (size_t)64 * E_DIM;              // advance direct base one chunk
    __syncthreads();                         // drains own stage (full-chunk
                                             // overlap); rotates buffers
  }

  // Once-per-block reduce of e over the 16-lane col group + pl store.
  #pragma unroll
  for (int i = 0; i < 8; i++) {
    float s = e[i];
    #pragma unroll
    for (int m = 1; m < 16; m <<= 1) s += __shfl_xor(s, m, 64);
    if (l15 == 0) {
      int grow = row0 + (i >> 2) * 16 + 4 * q + (i & 3);
      pl[(size_t)grow * NGRP + grp] = s;
    }
  }
}

// Single block, 1024 threads: 4 rows/thread, block-reduce, direct store.
__global__ __launch_bounds__(1024) void k_reduce(const float* __restrict__ pl,
                                                 const float* __restrict__ tv,
                                                 const float* __restrict__ tb,
                                                 float* __restrict__ out) {
  int tid = threadIdx.x;
  float acc = 0.f;
  for (int row = tid; row < N_ROWS; row += 1024) {
    const float4* p = (const float4*)(pl + (size_t)row * NGRP);
    float4 s0 = p[0], s1 = p[1], s2 = p[2], s3 = p[3];
    float S = (s0.x + s0.y + s0.z + s0.w) + (s1.x + s1.y + s1.z + s1.w)
            + (s2.x + s2.y + s2.z + s2.w) + (s3.x + s3.y + s3.z + s3.w);
    float t = tv[row];
    float tbl = tb[row];
    float sint = sqrtf(fmaxf(0.f, 1.f - t * t));
    float cosm = t * COS_M - sint * SIN_M;
    float Sp = S - __expf(tbl) + __expf(cosm);
    acc += logf(Sp) - cosm;
  }
  #pragma unroll
  for (int m = 32; m > 0; m >>= 1) acc += __shfl_xor(acc, m, 64);
  __shared__ float sb[16];
  if ((tid & 63) == 0) sb[tid >> 6] = acc;
  __syncthreads();
  if (tid == 0) {
    float S = 0.f;
    #pragma unroll
    for (int i = 0; i < 16; i++) S += sb[i];
    out[0] = S * (1.0f / N_ROWS);
  }
}

extern "C" void kernel_launch(void* const* d_in, const int* in_sizes, int n_in,
                              void* d_out, int out_size, void* d_ws, size_t ws_size,
                              hipStream_t stream) {
  const float* x = (const float*)d_in[0];
  const int* label = (const int*)d_in[1];
  const float* w = (const float*)d_in[2];
  float* out = (float*)d_out;
  char* ws = (char*)d_ws;

  size_t off = 0;
  unsigned short* nx = (unsigned short*)(ws + off); off += (size_t)N_ROWS * E_DIM * 2;  // 4 MB
  unsigned short* nw = (unsigned short*)(ws + off); off += (size_t)C_CLS * E_DIM * 2;   // 51.5 MB
  float* tv  = (float*)(ws + off); off += (size_t)N_ROWS * 4;
  float* tb  = (float*)(ws + off); off += (size_t)N_ROWS * 4;
  float* pl  = (float*)(ws + off); off += (size_t)N_ROWS * NGRP * 4;                    // 256 KB

  int nwBlocks = (C_CLS + 3) / 4;
  k_norm<<<N_ROWS + nwBlocks, 256, 0, stream>>>(x, w, label, nx, nw, tv, tb);
  dim3 g(16, 16);
  k_gemm<<<g, 512, 0, stream>>>(nx, nw, pl);
  k_reduce<<<1, 1024, 0, stream>>>(pl, tv, tb, out);
}

// Round 8
// 429.336 us; speedup vs baseline: 1.3908x; 1.3836x over previous
//
#include <hip/hip_runtime.h>
#include <math.h>

#define N_ROWS 4096
#define E_DIM  512
#define C_CLS  50257
#define NCH    786            // ceil(50257/64) col chunks of 64
#define NGRP   16             // col groups (blockIdx.y); pl = [N_ROWS][NGRP]
#define COS_M  (-0.6536436208636119f)   // cos(4.0)
#define SIN_M  (-0.7568024953079282f)   // sin(4.0)
#define EPSN   1e-12f

typedef __bf16 bf16x8 __attribute__((ext_vector_type(8)));
typedef float  f32x4  __attribute__((ext_vector_type(4)));
typedef unsigned short ushort8 __attribute__((ext_vector_type(8)));

__device__ inline unsigned short f2bf(float f) {
  unsigned int u = __float_as_uint(f);
  u += 0x7FFFu + ((u >> 16) & 1u);     // round-to-nearest-even
  return (unsigned short)(u >> 16);
}
__device__ inline float bf2f(unsigned short u) {
  return __uint_as_float((unsigned)u << 16);
}

// Fused normalize kernel:
//  blocks [0, N_ROWS)   : x-row L2-normalize + fp32 target cos tv +
//                         bf16-rounded target cos tb.
//  blocks [N_ROWS, ...) : w-row L2-normalize (4 rows/block).
__global__ __launch_bounds__(256) void k_norm(const float* __restrict__ x,
                                              const float* __restrict__ w,
                                              const int* __restrict__ label,
                                              unsigned short* __restrict__ nx,
                                              unsigned short* __restrict__ nw,
                                              float* __restrict__ tv,
                                              float* __restrict__ tb) {
  if (blockIdx.x >= N_ROWS) {
    int row = (blockIdx.x - N_ROWS) * 4 + (threadIdx.x >> 6);
    if (row >= C_CLS) return;
    int lane = threadIdx.x & 63;
    const float4* p = (const float4*)(w + (size_t)row * E_DIM);
    float4 v0 = p[lane * 2], v1 = p[lane * 2 + 1];
    float ss = v0.x*v0.x + v0.y*v0.y + v0.z*v0.z + v0.w*v0.w
             + v1.x*v1.x + v1.y*v1.y + v1.z*v1.z + v1.w*v1.w;
    #pragma unroll
    for (int m = 32; m > 0; m >>= 1) ss += __shfl_xor(ss, m, 64);
    float inv = 1.0f / fmaxf(sqrtf(ss), EPSN);
    ushort8 o;
    o[0]=f2bf(v0.x*inv); o[1]=f2bf(v0.y*inv); o[2]=f2bf(v0.z*inv); o[3]=f2bf(v0.w*inv);
    o[4]=f2bf(v1.x*inv); o[5]=f2bf(v1.y*inv); o[6]=f2bf(v1.z*inv); o[7]=f2bf(v1.w*inv);
    *(ushort8*)(nw + (size_t)row * E_DIM + lane * 8) = o;
    return;
  }
  int row = blockIdx.x;
  int lab = label[row];
  int tid = threadIdx.x;
  const float2* px = (const float2*)(x + (size_t)row * E_DIM);
  const float2* pw = (const float2*)(w + (size_t)lab * E_DIM);
  float2 a = px[tid], b = pw[tid];
  float sx = a.x*a.x + a.y*a.y;
  float sw = b.x*b.x + b.y*b.y;
  float sd = a.x*b.x + a.y*b.y;
  #pragma unroll
  for (int off = 32; off > 0; off >>= 1) {
    sx += __shfl_down(sx, off, 64);
    sw += __shfl_down(sw, off, 64);
    sd += __shfl_down(sd, off, 64);
  }
  __shared__ float sb[3][4];
  __shared__ float sb2[4];
  if ((tid & 63) == 0) {
    sb[0][tid >> 6] = sx; sb[1][tid >> 6] = sw; sb[2][tid >> 6] = sd;
  }
  __syncthreads();
  float SX = sb[0][0] + sb[0][1] + sb[0][2] + sb[0][3];
  float SW = sb[1][0] + sb[1][1] + sb[1][2] + sb[1][3];
  float invx = 1.0f / fmaxf(sqrtf(SX), EPSN);
  float invw = 1.0f / fmaxf(sqrtf(SW), EPSN);
  ushort2 o;
  o.x = f2bf(a.x * invx);
  o.y = f2bf(a.y * invx);
  ((ushort2*)(nx + (size_t)row * E_DIM))[tid] = o;
  float s2 = bf2f(o.x) * bf2f(f2bf(b.x * invw))
           + bf2f(o.y) * bf2f(f2bf(b.y * invw));
  #pragma unroll
  for (int off = 32; off > 0; off >>= 1) s2 += __shfl_down(s2, off, 64);
  if ((tid & 63) == 0) sb2[tid >> 6] = s2;
  __syncthreads();
  if (tid == 0) {
    float SD = sb[2][0] + sb[2][1] + sb[2][2] + sb[2][3];
    tv[row] = SD / (fmaxf(sqrtf(SX), EPSN) * fmaxf(sqrtf(SW), EPSN));
    tb[row] = sb2[0] + sb2[1] + sb2[2] + sb2[3];
  }
}

// ---------------------------------------------------------------------------
// Persistent column-streaming GEMM — 64-ROW WAVES (LDS-traffic halved).
//
// Register model learned in r4-r7: unified VGPR+AGPR budget per wave;
// VGPR_Count reports ARCH only (r4's 116 proves A lived in AGPRs); the r6/r7
// dual-port design needed ~274 unified regs at a 256 budget -> spilled
// (WRITE_SIZE 6.9 MB) regardless of launch bounds. Per-wave B LDS-read is
// fixed at the tile size, so LDS bytes per MFMA scale as 1/rows-per-wave:
// go to 64 rows/wave. A-slab = 64 rows x K=512 = 256 frags -> AGPR file
// exactly; acc[4][4]=64 + bfr 16 + e 16 + addr ~40 arch. Needs the 512-reg
// budget of 1 wave/SIMD: block = 4 waves x 64 rows = 256-row tile (grid
// unchanged 16x16); LDS 2x64 KB already caps at 1 block/CU, so 4 waves/CU
// costs nothing extra.
//
// Per-chunk floors per CU: MFMA 1024 x ~19.4 cyc/SIMD = 5.0K (bound);
// LDS 64 KB stage-write + 4x64 KB read = 320 KB ~= 3.2K; exp epilogue
// ~0.6K serial. Single-wave MFMA feeding is fine: 16 independent acc
// chains per ks-step; compiler pipelines the 4 ds_read_b128 per ks under
// the ~310 cyc of MFMA.
//
// A loaded in 4 batches of 16 volatile-asm global_load_dwordx4 (peak arch
// pressure ~80 during prologue; asm = not sinkable/rematerializable).
// One barrier per chunk; its vmcnt(0) drains the stage issued a full chunk
// (~6K cyc) earlier -> free. Thin interior epilogue; masked tail chunk only.
// ---------------------------------------------------------------------------
#define GLDS(gp, lp) __builtin_amdgcn_global_load_lds( \
    (const __attribute__((address_space(1))) void*)(gp), \
    (__attribute__((address_space(3))) void*)(lp), 16, 0, 0)

__global__ __launch_bounds__(256, 1) void k_gemm(const unsigned short* __restrict__ nx,
                                                 const unsigned short* __restrict__ nw,
                                                 float* __restrict__ pl) {
  __shared__ unsigned char ldsB[2][65536];   // 2 x (64 cols x 512 k x 2 B)

  const int rtile = blockIdx.x;              // 0..15
  const int grp   = blockIdx.y;              // 0..15
  const int c0    = grp * 49 + (grp < 2 ? grp : 2);   // chunk range [c0, c1)
  const int c1    = c0 + 49 + (grp < 2 ? 1 : 0);      // groups 0,1 take 50

  const int tid  = threadIdx.x;
  const int wave = tid >> 6;                 // 0..3
  const int lane = tid & 63;
  const int q    = lane >> 4;
  const int l15  = lane & 15;
  const int row0 = rtile * 256 + wave * 64;  // wave's first output row

  // Stage chunk c into buffer p: 64 KB = 64 1-KB fragment chunks,
  // ch = cf*16+ks covers cols [cf*16,+16) x k [ks*32,+32); wave w stages
  // ch in [w*16, w*16+16) (16 GLDS/thread). Lane (q,l15) supplies col
  // cf*16+l15, k ks*32+q*8..+7 -> lands linear at base+lane*16.
  auto stageB = [&](int c, int p) {
    unsigned cb = (unsigned)c * 64u;
    #pragma unroll
    for (int i = 0; i < 16; i++) {
      int ch = wave * 16 + i;                // wave-uniform; cf = wave
      unsigned col = cb + (unsigned)(wave * 16 + l15);
      unsigned off = col * (unsigned)E_DIM + (unsigned)(i * 32 + q * 8);
      GLDS(nw + off, &ldsB[p][ch * 1024]);   // OOB (grp 15 tail) lands in ws
    }
  };

  // Issue first LDS stage, then load A-slab while it flies.
  stageB(c0, c0 & 1);

  // A-slab: 64 rows x K=512 = 256 fragments, loaded in 4 batches of 16
  // volatile-asm loads (keeps peak arch-VGPR pressure low; values then
  // migrate to AGPRs as MFMA A-operands).
  bf16x8 a[4][16];
  #pragma unroll
  for (int rf = 0; rf < 4; rf++) {
    f32x4 tmp[16];
    #pragma unroll
    for (int kf = 0; kf < 16; kf++) {
      const unsigned short* pa = nx + (size_t)(row0 + rf * 16 + l15) * E_DIM
                                    + kf * 32 + q * 8;
      asm volatile("global_load_dwordx4 %0, %1, off"
                   : "=v"(tmp[kf]) : "v"(pa));
    }
    asm volatile("s_waitcnt vmcnt(0)" ::: "memory");
    #pragma unroll
    for (int kf = 0; kf < 16; kf++)
      a[rf][kf] = __builtin_bit_cast(bf16x8, tmp[kf]);
  }

  float e[16] = {};                          // per-lane partial exp-sums

  __syncthreads();                           // chunk c0 landed everywhere

  for (int c = c0; c < c1; ++c) {
    const int p = c & 1;
    if (c + 1 < c1) stageB(c + 1, p ^ 1);    // depth-1 prefetch (other buffer)

    f32x4 acc[4][4] = {};
    const unsigned char* bb = &ldsB[p][0];
    #pragma unroll
    for (int ks = 0; ks < 16; ks++) {
      bf16x8 bfr[4];
      #pragma unroll
      for (int cf = 0; cf < 4; cf++)
        bfr[cf] = *(const bf16x8*)(bb + (unsigned)((cf * 16 + ks) * 1024)
                                      + (unsigned)lane * 16u);
      #pragma unroll
      for (int rf = 0; rf < 4; rf++)
        #pragma unroll
        for (int cf = 0; cf < 4; cf++)
          acc[rf][cf] = __builtin_amdgcn_mfma_f32_16x16x32_bf16(
              a[rf][ks], bfr[cf], acc[rf][cf], 0, 0, 0);
    }

    // Thin per-chunk epilogue: exp + accumulate; compares only in the tail.
    if (c != NCH - 1) {
      #pragma unroll
      for (int rf = 0; rf < 4; rf++)
        #pragma unroll
        for (int r = 0; r < 4; r++)
          #pragma unroll
          for (int cf = 0; cf < 4; cf++)
            e[rf * 4 + r] += __expf(acc[rf][cf][r]);
    } else {
      const int ccol = c * 64;
      #pragma unroll
      for (int rf = 0; rf < 4; rf++)
        #pragma unroll
        for (int r = 0; r < 4; r++)
          #pragma unroll
          for (int cf = 0; cf < 4; cf++) {
            int col = ccol + cf * 16 + l15;
            if (col < C_CLS) e[rf * 4 + r] += __expf(acc[rf][cf][r]);
          }
    }

    __syncthreads();   // vmcnt(0): stage c+1 landed (covered by ~6K-cyc chunk);
                       // lgkmcnt(0): my buf-p reads retired; barrier: all waves
                       // done with buf p -> next iter may stage c+2 into it.
  }

  // Once-per-block reduce of e over the 16-lane col group + pl store.
  #pragma unroll
  for (int i = 0; i < 16; i++) {
    float s = e[i];
    #pragma unroll
    for (int m = 1; m < 16; m <<= 1) s += __shfl_xor(s, m, 64);
    if (l15 == 0) {
      int grow = row0 + (i >> 2) * 16 + 4 * q + (i & 3);
      pl[(size_t)grow * NGRP + grp] = s;
    }
  }
}

// Single block, 1024 threads: 4 rows/thread, block-reduce, direct store.
__global__ __launch_bounds__(1024) void k_reduce(const float* __restrict__ pl,
                                                 const float* __restrict__ tv,
                                                 const float* __restrict__ tb,
                                                 float* __restrict__ out) {
  int tid = threadIdx.x;
  float acc = 0.f;
  for (int row = tid; row < N_ROWS; row += 1024) {
    const float4* p = (const float4*)(pl + (size_t)row * NGRP);
    float4 s0 = p[0], s1 = p[1], s2 = p[2], s3 = p[3];
    float S = (s0.x + s0.y + s0.z + s0.w) + (s1.x + s1.y + s1.z + s1.w)
            + (s2.x + s2.y + s2.z + s2.w) + (s3.x + s3.y + s3.z + s3.w);
    float t = tv[row];
    float tbl = tb[row];
    float sint = sqrtf(fmaxf(0.f, 1.f - t * t));
    float cosm = t * COS_M - sint * SIN_M;
    float Sp = S - __expf(tbl) + __expf(cosm);
    acc += logf(Sp) - cosm;
  }
  #pragma unroll
  for (int m = 32; m > 0; m >>= 1) acc += __shfl_xor(acc, m, 64);
  __shared__ float sb[16];
  if ((tid & 63) == 0) sb[tid >> 6] = acc;
  __syncthreads();
  if (tid == 0) {
    float S = 0.f;
    #pragma unroll
    for (int i = 0; i < 16; i++) S += sb[i];
    out[0] = S * (1.0f / N_ROWS);
  }
}

extern "C" void kernel_launch(void* const* d_in, const int* in_sizes, int n_in,
                              void* d_out, int out_size, void* d_ws, size_t ws_size,
                              hipStream_t stream) {
  const float* x = (const float*)d_in[0];
  const int* label = (const int*)d_in[1];
  const float* w = (const float*)d_in[2];
  float* out = (float*)d_out;
  char* ws = (char*)d_ws;

  size_t off = 0;
  unsigned short* nx = (unsigned short*)(ws + off); off += (size_t)N_ROWS * E_DIM * 2;  // 4 MB
  unsigned short* nw = (unsigned short*)(ws + off); off += (size_t)C_CLS * E_DIM * 2;   // 51.5 MB
  float* tv  = (float*)(ws + off); off += (size_t)N_ROWS * 4;
  float* tb  = (float*)(ws + off); off += (size_t)N_ROWS * 4;
  float* pl  = (float*)(ws + off); off += (size_t)N_ROWS * NGRP * 4;                    // 256 KB

  int nwBlocks = (C_CLS + 3) / 4;
  k_norm<<<N_ROWS + nwBlocks, 256, 0, stream>>>(x, w, label, nx, nw, tv, tb);
  dim3 g(16, 16);
  k_gemm<<<g, 256, 0, stream>>>(nx, nw, pl);
  k_reduce<<<1, 1024, 0, stream>>>(pl, tv, tb, out);
}

// Round 9
// 310.381 us; speedup vs baseline: 1.9238x; 1.3833x over previous
//
#include <hip/hip_runtime.h>
#include <math.h>

#define N_ROWS 4096
#define E_DIM  512
#define C_CLS  50257
#define NCH    786            // ceil(50257/64) col chunks of 64
#define NGRP   16             // col groups (blockIdx.y); pl = [N_ROWS][NGRP]
#define COS_M  (-0.6536436208636119f)   // cos(4.0)
#define SIN_M  (-0.7568024953079282f)   // sin(4.0)
#define EPSN   1e-12f
#define FSCL   16.0f          // fp8 pre-scale per operand (dot scaled by 256)
#define IFS2   0.00390625f    // 1/256

typedef float  f32x4  __attribute__((ext_vector_type(4)));
typedef int    i32x2  __attribute__((ext_vector_type(2)));

__device__ inline float bf2f(unsigned short u) {
  return __uint_as_float((unsigned)u << 16);
}

// Fused normalize kernel -> fp8 e4m3 outputs (x16 scale on each operand):
//  blocks [0, N_ROWS)   : x-row L2-normalize -> nx fp8; fp32 target cos tv;
//                         fp8-roundtrip target cos tb (matches GEMM's label
//                         logit up to fp32 sum order).
//  blocks [N_ROWS, ...) : w-row L2-normalize -> nw fp8 (4 rows/block).
__global__ __launch_bounds__(256) void k_norm(const float* __restrict__ x,
                                              const float* __restrict__ w,
                                              const int* __restrict__ label,
                                              unsigned char* __restrict__ nx,
                                              unsigned char* __restrict__ nw,
                                              float* __restrict__ tv,
                                              float* __restrict__ tb) {
  if (blockIdx.x >= N_ROWS) {
    int row = (blockIdx.x - N_ROWS) * 4 + (threadIdx.x >> 6);
    if (row >= C_CLS) return;
    int lane = threadIdx.x & 63;
    const float4* p = (const float4*)(w + (size_t)row * E_DIM);
    float4 v0 = p[lane * 2], v1 = p[lane * 2 + 1];
    float ss = v0.x*v0.x + v0.y*v0.y + v0.z*v0.z + v0.w*v0.w
             + v1.x*v1.x + v1.y*v1.y + v1.z*v1.z + v1.w*v1.w;
    #pragma unroll
    for (int m = 32; m > 0; m >>= 1) ss += __shfl_xor(ss, m, 64);
    float inv = FSCL / fmaxf(sqrtf(ss), EPSN);
    int lo = __builtin_amdgcn_cvt_pk_fp8_f32(v0.x*inv, v0.y*inv, 0, 0);
    lo     = __builtin_amdgcn_cvt_pk_fp8_f32(v0.z*inv, v0.w*inv, lo, 1);
    int hi = __builtin_amdgcn_cvt_pk_fp8_f32(v1.x*inv, v1.y*inv, 0, 0);
    hi     = __builtin_amdgcn_cvt_pk_fp8_f32(v1.z*inv, v1.w*inv, hi, 1);
    i32x2 o; o[0] = lo; o[1] = hi;
    *(i32x2*)(nw + (size_t)row * E_DIM + lane * 8) = o;
    return;
  }
  int row = blockIdx.x;
  int lab = label[row];
  int tid = threadIdx.x;
  const float2* px = (const float2*)(x + (size_t)row * E_DIM);
  const float2* pw = (const float2*)(w + (size_t)lab * E_DIM);
  float2 a = px[tid], b = pw[tid];
  float sx = a.x*a.x + a.y*a.y;
  float sw = b.x*b.x + b.y*b.y;
  float sd = a.x*b.x + a.y*b.y;
  #pragma unroll
  for (int off = 32; off > 0; off >>= 1) {
    sx += __shfl_down(sx, off, 64);
    sw += __shfl_down(sw, off, 64);
    sd += __shfl_down(sd, off, 64);
  }
  __shared__ float sb[3][4];
  __shared__ float sb2[4];
  if ((tid & 63) == 0) {
    sb[0][tid >> 6] = sx; sb[1][tid >> 6] = sw; sb[2][tid >> 6] = sd;
  }
  __syncthreads();
  float SX = sb[0][0] + sb[0][1] + sb[0][2] + sb[0][3];
  float SW = sb[1][0] + sb[1][1] + sb[1][2] + sb[1][3];
  float invx = FSCL / fmaxf(sqrtf(SX), EPSN);
  float invw = FSCL / fmaxf(sqrtf(SW), EPSN);
  // nx fp8: 2 elems/thread.
  int pxq = __builtin_amdgcn_cvt_pk_fp8_f32(a.x*invx, a.y*invx, 0, 0);
  *(unsigned short*)(nx + (size_t)row * E_DIM + tid * 2) = (unsigned short)(pxq & 0xFFFF);
  // fp8 round-trip dot for tb (same quantization the GEMM sees).
  int pwq = __builtin_amdgcn_cvt_pk_fp8_f32(b.x*invw, b.y*invw, 0, 0);
  float f0 = __builtin_amdgcn_cvt_f32_fp8(pxq, 0);
  float f1 = __builtin_amdgcn_cvt_f32_fp8(pxq, 1);
  float g0 = __builtin_amdgcn_cvt_f32_fp8(pwq, 0);
  float g1 = __builtin_amdgcn_cvt_f32_fp8(pwq, 1);
  float s2 = f0 * g0 + f1 * g1;
  #pragma unroll
  for (int off = 32; off > 0; off >>= 1) s2 += __shfl_down(s2, off, 64);
  if ((tid & 63) == 0) sb2[tid >> 6] = s2;
  __syncthreads();
  if (tid == 0) {
    float SD = sb[2][0] + sb[2][1] + sb[2][2] + sb[2][3];
    tv[row] = SD / (fmaxf(sqrtf(SX), EPSN) * fmaxf(sqrtf(SW), EPSN));
    tb[row] = (sb2[0] + sb2[1] + sb2[2] + sb2[3]) * IFS2;
  }
}

// ---------------------------------------------------------------------------
// Persistent column-streaming GEMM — FP8 operands, r4 schedule.
//
// r4-r8 conclusions: the 8-wave/32-row/2-per-SIMD schedule (r4, 180 us) is
// the right one (r8's 1-wave/SIMD lost MFMA/VALU overlap and regressed); r4
// is LDS-BYTE-bound (576 KB/chunk ~6.9K cyc > MFMA 5.0K); rows/wave and
// dual-port are register-infeasible. FP8 e4m3 (non-scaled, = bf16 MFMA rate)
// halves every byte: LDS/chunk = 8x32 read + 32 stage = 288 KB ~3.4K cyc
// < MFMA 5.0K -> MFMA-bound. A-slab drops to 64 regs.
//
// LDS layout: col-major, 512 B per col (64 cols = 32 KB/buffer), with a
// 16-B-granularity XOR swizzle: 16-B k-block kb of col lcol stored at
// lcol*512 + ((kb ^ (lcol&7))<<4). Staging: GLDS dst = uniform base +
// lane*16 (lcol = lp + (lane>>5), kb = lane&31 -> exactly lane*16); src =
// per-lane pre-swizzled global address (both-sides involution, rule 21).
// ds_read_b64 for frag (cf,ks): quarter-wave banks = 4*(kb^ (l15&7)) -> 8
// groups x 2 lanes = 2-way = free (m136). LDS padded 2x48 KB -> 1 block/CU.
//
// Per chunk: stage(c+1) [4 GLDS] -> 16 ks x {4 ds_read_b64 + 8 MFMA} ->
// 32 exp (x 1/256 unscale) -> __syncthreads (vmcnt drain covered by chunk).
// tb/label logic lives in k_norm; tail chunk masks col >= C_CLS.
// ---------------------------------------------------------------------------
#define GLDS(gp, lp) __builtin_amdgcn_global_load_lds( \
    (const __attribute__((address_space(1))) void*)(gp), \
    (__attribute__((address_space(3))) void*)(lp), 16, 0, 0)

__global__ __launch_bounds__(512) void k_gemm(const unsigned char* __restrict__ nx,
                                              const unsigned char* __restrict__ nw,
                                              float* __restrict__ pl) {
  __shared__ unsigned char ldsB[2][49152];   // use first 32 KB each; pad->1 blk/CU

  const int rtile = blockIdx.x;              // 0..15
  const int grp   = blockIdx.y;              // 0..15
  const int c0    = grp * 49 + (grp < 2 ? grp : 2);   // chunk range [c0, c1)
  const int c1    = c0 + 49 + (grp < 2 ? 1 : 0);      // groups 0,1 take 50

  const int tid  = threadIdx.x;
  const int wave = tid >> 6;                 // 0..7
  const int lane = tid & 63;
  const int q    = lane >> 4;
  const int l15  = lane & 15;
  const int row0 = rtile * 256 + wave * 32;  // wave's first output row

  // Stage chunk c (cols [c*64, +64), full K) into buffer p. Wave w owns
  // local cols [w*8, w*8+8) = 4 GLDS of 2 cols each. Lane: lcol = lp +
  // (lane>>5), kb = lane&31; dst = base(lp*512) + lane*16 (wave-uniform
  // base); src fetches k-block kb ^ (lcol&7) of global col (pre-swizzle).
  auto stageB = [&](int c, int p) {
    unsigned cb = (unsigned)c * 64u;
    #pragma unroll
    for (int i = 0; i < 4; i++) {
      int lp = wave * 8 + i * 2;             // wave-uniform local col base
      unsigned lcol = (unsigned)lp + ((unsigned)lane >> 5);
      unsigned kb   = (unsigned)lane & 31u;
      const unsigned char* src = nw + (size_t)(cb + lcol) * E_DIM
                                    + ((kb ^ (lcol & 7u)) << 4);
      GLDS(src, &ldsB[p][lp * 512]);         // OOB (grp 15 tail) lands in ws
    }
  };

  // Issue first stage, then load A-slab while it flies.
  stageB(c0, c0 & 1);

  // A-slab: 32 rows x K=512 fp8 = 64 regs, pinned via volatile asm loads
  // (r2/r3 lesson: plain loads get re-materialized from memory every chunk).
  i32x2 a[2][16];
  #pragma unroll
  for (int rf = 0; rf < 2; rf++)
    #pragma unroll
    for (int kf = 0; kf < 16; kf++) {
      const unsigned char* pa = nx + (size_t)(row0 + rf * 16 + l15) * E_DIM
                                   + kf * 32 + q * 8;
      asm volatile("global_load_dwordx2 %0, %1, off"
                   : "=v"(a[rf][kf]) : "v"(pa));
    }
  asm volatile("s_waitcnt vmcnt(0)" ::: "memory");

  float e[8] = {};                           // per-lane partial exp-sums

  __syncthreads();                           // chunk c0 landed everywhere

  // Per-lane invariant read offsets.
  const unsigned lbase = (unsigned)l15 * 512u + (unsigned)((q & 1) * 8);
  const unsigned lswz  = (unsigned)(l15 & 7);
  const unsigned qh    = (unsigned)(q >> 1);

  for (int c = c0; c < c1; ++c) {
    const int p = c & 1;
    if (c + 1 < c1) stageB(c + 1, p ^ 1);    // depth-1 prefetch (other buffer)

    f32x4 acc[2][4] = {};
    const unsigned char* bb = &ldsB[p][0];
    #pragma unroll
    for (int ks = 0; ks < 16; ks++) {
      unsigned kx = (((unsigned)(2 * ks) + qh) ^ lswz) << 4;
      long bfr[4];
      #pragma unroll
      for (int cf = 0; cf < 4; cf++) {
        i32x2 bv = *(const i32x2*)(bb + (unsigned)cf * 8192u + lbase + kx);
        bfr[cf] = __builtin_bit_cast(long, bv);
      }
      #pragma unroll
      for (int rf = 0; rf < 2; rf++) {
        long av = __builtin_bit_cast(long, a[rf][ks]);
        #pragma unroll
        for (int cf = 0; cf < 4; cf++)
          acc[rf][cf] = __builtin_amdgcn_mfma_f32_16x16x32_fp8_fp8(
              av, bfr[cf], acc[rf][cf], 0, 0, 0);
      }
    }

    // Thin epilogue: unscale (1/256), exp, accumulate; mask only in tail.
    if (c != NCH - 1) {
      #pragma unroll
      for (int rf = 0; rf < 2; rf++)
        #pragma unroll
        for (int r = 0; r < 4; r++)
          #pragma unroll
          for (int cf = 0; cf < 4; cf++)
            e[rf * 4 + r] += __expf(acc[rf][cf][r] * IFS2);
    } else {
      const int ccol = c * 64;
      #pragma unroll
      for (int rf = 0; rf < 2; rf++)
        #pragma unroll
        for (int r = 0; r < 4; r++)
          #pragma unroll
          for (int cf = 0; cf < 4; cf++) {
            int col = ccol + cf * 16 + l15;
            if (col < C_CLS) e[rf * 4 + r] += __expf(acc[rf][cf][r] * IFS2);
          }
    }

    __syncthreads();   // vmcnt(0): stage c+1 landed (covered by chunk work);
                       // lgkmcnt(0): my buf-p reads retired; barrier: all waves
                       // done with buf p -> next iter may stage c+2 into it.
  }

  // Once-per-block reduce of e over the 16-lane col group + pl store.
  #pragma unroll
  for (int i = 0; i < 8; i++) {
    float s = e[i];
    #pragma unroll
    for (int m = 1; m < 16; m <<= 1) s += __shfl_xor(s, m, 64);
    if (l15 == 0) {
      int grow = row0 + (i >> 2) * 16 + 4 * q + (i & 3);
      pl[(size_t)grow * NGRP + grp] = s;
    }
  }
}

// Single block, 1024 threads: 4 rows/thread, block-reduce, direct store.
__global__ __launch_bounds__(1024) void k_reduce(const float* __restrict__ pl,
                                                 const float* __restrict__ tv,
                                                 const float* __restrict__ tb,
                                                 float* __restrict__ out) {
  int tid = threadIdx.x;
  float acc = 0.f;
  for (int row = tid; row < N_ROWS; row += 1024) {
    const float4* p = (const float4*)(pl + (size_t)row * NGRP);
    float4 s0 = p[0], s1 = p[1], s2 = p[2], s3 = p[3];
    float S = (s0.x + s0.y + s0.z + s0.w) + (s1.x + s1.y + s1.z + s1.w)
            + (s2.x + s2.y + s2.z + s2.w) + (s3.x + s3.y + s3.z + s3.w);
    float t = tv[row];
    float tbl = tb[row];
    float sint = sqrtf(fmaxf(0.f, 1.f - t * t));
    float cosm = t * COS_M - sint * SIN_M;
    float Sp = S - __expf(tbl) + __expf(cosm);
    acc += logf(Sp) - cosm;
  }
  #pragma unroll
  for (int m = 32; m > 0; m >>= 1) acc += __shfl_xor(acc, m, 64);
  __shared__ float sb[16];
  if ((tid & 63) == 0) sb[tid >> 6] = acc;
  __syncthreads();
  if (tid == 0) {
    float S = 0.f;
    #pragma unroll
    for (int i = 0; i < 16; i++) S += sb[i];
    out[0] = S * (1.0f / N_ROWS);
  }
}

extern "C" void kernel_launch(void* const* d_in, const int* in_sizes, int n_in,
                              void* d_out, int out_size, void* d_ws, size_t ws_size,
                              hipStream_t stream) {
  const float* x = (const float*)d_in[0];
  const int* label = (const int*)d_in[1];
  const float* w = (const float*)d_in[2];
  float* out = (float*)d_out;
  char* ws = (char*)d_ws;

  size_t off = 0;
  unsigned char* nx = (unsigned char*)(ws + off); off += (size_t)N_ROWS * E_DIM;  // 2 MB
  unsigned char* nw = (unsigned char*)(ws + off); off += (size_t)C_CLS * E_DIM;   // 25.7 MB
  float* tv  = (float*)(ws + off); off += (size_t)N_ROWS * 4;
  float* tb  = (float*)(ws + off); off += (size_t)N_ROWS * 4;
  float* pl  = (float*)(ws + off); off += (size_t)N_ROWS * NGRP * 4;              // 256 KB

  int nwBlocks = (C_CLS + 3) / 4;
  k_norm<<<N_ROWS + nwBlocks, 256, 0, stream>>>(x, w, label, nx, nw, tv, tb);
  dim3 g(16, 16);
  k_gemm<<<g, 512, 0, stream>>>(nx, nw, pl);
  k_reduce<<<1, 1024, 0, stream>>>(pl, tv, tb, out);
}